// Round 4
// baseline (243.026 us; speedup 1.0000x reference)
//
#include <hip/hip_runtime.h>
#include <hip/hip_bf16.h>

#define BSZ 64
#define TMAX 200
#define TOUT 198
#define PCODES 40
#define NC 507      // NUM_CODE+1
#define KSEL 100
#define DOTH 57
#define TB 6
#define NBLK_T (TOUT/TB)   // 33
#define FWD_OFF 0
#define BWD_OFF 3244032
#define FV_OFF  6488064

__global__ __launch_bounds__(256) void main_kernel(
    const int* __restrict__ code, const float* __restrict__ others,
    const int* __restrict__ length,
    const int* __restrict__ target, const int* __restrict__ weight_idx,
    const float* __restrict__ Wf, const float* __restrict__ bfv,
    const float* __restrict__ Wb, const float* __restrict__ bbv,
    const float* __restrict__ W0, const float* __restrict__ b0,
    const float* __restrict__ W1, const float* __restrict__ b1,
    float* __restrict__ out)
{
  const int b  = blockIdx.y;
  const int t0 = blockIdx.x * TB;
  const int n  = threadIdx.x;
  const int L  = length[b];

  __shared__ int   cc[3][TB][PCODES];   // s=0 fwd (t), s=1 mlp (t+1), s=2 bwd (rt)
  __shared__ float cfl[3][TB][PCODES];  // 1.0 first occurrence, 0.0 duplicate
  __shared__ float oF[TB][57];
  __shared__ float oB[TB][57];
  __shared__ float oM[TB][48];
  __shared__ float h0s[TB][256];
  __shared__ float red[TB][4];
  __shared__ int   wsel[KSEL];
  __shared__ int   tg[10];
  __shared__ float tval[KSEL];

  // ---- stage target/weight_idx + codes ----
  if (n < KSEL) wsel[n] = weight_idx[n];
  else if (n < KSEL + 10) tg[n - KSEL] = target[b*10 + (n - KSEL)];
  for (int idx = n; idx < 3*TB*PCODES; idx += 256) {
    int p   = idx % PCODES;
    int rem = idx / PCODES;
    int tt  = rem % TB;
    int s   = rem / TB;
    int t   = t0 + tt;
    int row;
    if (s == 0)      row = t;
    else if (s == 1) row = t + 1;
    else             row = (t < L) ? (L - 1 - t) : t;
    cc[s][tt][p] = code[(b*TMAX + row)*PCODES + p];
  }
  __syncthreads();
  // ---- tval flags: 1 - multi_hot(target)[weight_idx[k]] ----
  if (n < KSEL) {
    int w = wsel[n];
    float v = 1.f;
    #pragma unroll
    for (int i = 0; i < 10; i++) if (tg[i] == w) v = 0.f;
    tval[n] = v;
  }
  // ---- dedup flags (multi_hot .set is idempotent) ----
  for (int idx = n; idx < 3*TB*PCODES; idx += 256) {
    int p   = idx % PCODES;
    int rem = idx / PCODES;
    int tt  = rem % TB;
    int s   = rem / TB;
    int c = cc[s][tt][p];
    float f = 1.f;
    for (int q = 0; q < p; q++) if (cc[s][tt][q] == c) { f = 0.f; break; }
    cfl[s][tt][p] = f;
  }
  // ---- stage dense others slices ----
  for (int idx = n; idx < TB*57; idx += 256) {
    int j = idx % 57, tt = idx / 57;
    int t = t0 + tt;
    int col = (j < 27) ? j : (j < 47 ? 37 + (j-27) : 27 + (j-47));
    oF[tt][j] = others[(b*TMAX + t)*DOTH + col];
    int rt = (t < L) ? (L - 1 - t) : t;
    float vb;
    if (j < 47) {
      vb = others[(b*TMAX + rt)*DOTH + col];
    } else if (t == 0) {
      vb = 0.f;
    } else {
      int rt2 = ((t-1) < L) ? (L - t) : (t - 1);
      vb = others[(b*TMAX + rt2)*DOTH + col];
    }
    oB[tt][j] = vb;
  }
  for (int idx = n; idx < TB*48; idx += 256) {
    int j = idx % 48, tt = idx / 48;
    int t = t0 + tt;
    int row, col;
    if (j < 20)      { row = t+1; col = 37 + j; }        // sign
    else if (j < 30) { row = t+1; col = 27 + (j-20); }   // interval_ first half
    else if (j < 40) { row = t+2; col = 27 + (j-30); }   // interval_ second half
    else             { row = t+1; col = 19 + (j-40); }   // stay
    oM[tt][j] = others[(b*TMAX + row)*DOTH + col];
  }
  __syncthreads();

  // ---- per-batch tgt fold ----
  float baseF = bfv[n];
  float baseB = bbv[n];
  for (int k = 0; k < KSEL; k++) {
    float v = tval[k];
    baseF = fmaf(v, Wf[(NC+k)*256 + n], baseF);
    baseB = fmaf(v, Wb[(NC+k)*256 + n], baseB);
  }

  float aF[TB], aB[TB], aM[TB];
  const float b0v = b0[n];
  #pragma unroll
  for (int tt = 0; tt < TB; tt++) { aF[tt]=baseF; aB[tt]=baseB; aM[tt]=b0v; }

  // ---- sparse multi-hot gathers (wave-coalesced row reads, L2-hot) ----
  #pragma unroll
  for (int tt = 0; tt < TB; tt++) {
    #pragma unroll 8
    for (int p = 0; p < PCODES; p++)
      aF[tt] = fmaf(cfl[0][tt][p], Wf[cc[0][tt][p]*256 + n], aF[tt]);
  }
  #pragma unroll
  for (int tt = 0; tt < TB; tt++) {
    #pragma unroll 8
    for (int p = 0; p < PCODES; p++)
      aM[tt] = fmaf(cfl[1][tt][p], W0[cc[1][tt][p]*256 + n], aM[tt]);
  }
  #pragma unroll
  for (int tt = 0; tt < TB; tt++) {
    #pragma unroll 8
    for (int p = 0; p < PCODES; p++)
      aB[tt] = fmaf(cfl[2][tt][p], Wb[cc[2][tt][p]*256 + n], aB[tt]);
  }

  // ---- dense dims: W row loaded once, reused across TB timesteps ----
  for (int j = 0; j < 57; j++) {
    float wf = Wf[(607+j)*256 + n];
    float wb = Wb[(607+j)*256 + n];
    #pragma unroll
    for (int tt = 0; tt < TB; tt++) {
      aF[tt] = fmaf(oF[tt][j], wf, aF[tt]);
      aB[tt] = fmaf(oB[tt][j], wb, aB[tt]);
    }
  }
  for (int j = 0; j < 48; j++) {
    float w0 = W0[(NC+j)*256 + n];
    #pragma unroll
    for (int tt = 0; tt < TB; tt++)
      aM[tt] = fmaf(oM[tt][j], w0, aM[tt]);
  }

  // ---- write x_forward / x_backward (f32 output) ----
  const int obase = b*TOUT*256;
  #pragma unroll
  for (int tt = 0; tt < TB; tt++) {
    int t = t0 + tt;
    out[FWD_OFF + obase + t*256 + n] = aF[tt];
    out[BWD_OFF + obase + t*256 + n] = aB[tt];
  }

  // ---- MLP layer 2: h0 -> LDS, W1 rows amortized over TB ----
  #pragma unroll
  for (int tt = 0; tt < TB; tt++) h0s[tt][n] = fmaxf(aM[tt], 0.f);
  __syncthreads();
  float a2[TB];
  const float b1v = b1[n];
  #pragma unroll
  for (int tt = 0; tt < TB; tt++) a2[tt] = b1v;
  for (int k = 0; k < 256; k++) {
    float w1 = W1[k*256 + n];
    #pragma unroll
    for (int tt = 0; tt < TB; tt++)
      a2[tt] = fmaf(h0s[tt][k], w1, a2[tt]);
  }

  // ---- L2 normalize + mask ----
  const int lane = n & 63, wv = n >> 6;
  #pragma unroll
  for (int tt = 0; tt < TB; tt++) {
    float v = a2[tt]*a2[tt];
    #pragma unroll
    for (int off = 32; off > 0; off >>= 1) v += __shfl_xor(v, off, 64);
    if (lane == 0) red[tt][wv] = v;
  }
  __syncthreads();
  #pragma unroll
  for (int tt = 0; tt < TB; tt++) {
    float s = red[tt][0] + red[tt][1] + red[tt][2] + red[tt][3];
    float inv = (s > 0.f) ? (1.0f / sqrtf(s)) : 0.f;
    int t = t0 + tt;
    float m = (t < L-2) ? 1.f : 0.f;
    out[FV_OFF + obase + t*256 + n] = a2[tt]*inv*m;
  }
}

extern "C" void kernel_launch(void* const* d_in, const int* in_sizes, int n_in,
                              void* d_out, int out_size, void* d_ws, size_t ws_size,
                              hipStream_t stream) {
  const int*   code    = (const int*)d_in[0];
  const float* others  = (const float*)d_in[1];
  const int*   length  = (const int*)d_in[2];
  const int*   target  = (const int*)d_in[3];
  const int*   widx    = (const int*)d_in[4];
  const float* Wf      = (const float*)d_in[5];
  const float* bfv     = (const float*)d_in[6];
  const float* Wb      = (const float*)d_in[7];
  const float* bbv     = (const float*)d_in[8];
  const float* W0      = (const float*)d_in[9];
  const float* b0v     = (const float*)d_in[10];
  const float* W1      = (const float*)d_in[11];
  const float* b1v     = (const float*)d_in[12];

  float* out = (float*)d_out;
  main_kernel<<<dim3(NBLK_T, BSZ), dim3(256), 0, stream>>>(code, others, length,
      target, widx, Wf, bfv, Wb, bbv, W0, b0v, W1, b1v, out);
}

// Round 5
// 176.084 us; speedup vs baseline: 1.3802x; 1.3802x over previous
//
#include <hip/hip_runtime.h>
#include <hip/hip_bf16.h>

typedef unsigned short u16;
typedef __attribute__((ext_vector_type(8))) short short8;
typedef __attribute__((ext_vector_type(4))) float f32x4;

#define TMAX 200
#define TOUT 198
#define PC 40
#define DOTH 57
#define NKT 9            // K tiles of 64 (K padded to 576)
#define FWD_OFF 0
#define BWD_OFF 3244032
#define FV_OFF  6488064
// ws byte offsets: packed bf16 weights + f32 tgt folds
#define OWF 0
#define OWB 294912
#define OW0 589824
#define OW1 884736
#define OTF 1015808
#define OTB 1081344

__device__ __forceinline__ u16 f2b(float v) {
  __hip_bfloat16 h = __float2bfloat16(v);
  return *(u16*)&h;
}

// Pack W into MFMA-friendly layout: dst[(k>>3)*256 + n)*8 + (k&7)] = bf16(W[remap(k)*256+n])
__global__ __launch_bounds__(256) void prep_pack(
    const float* __restrict__ Wf, const float* __restrict__ Wb,
    const float* __restrict__ W0, const float* __restrict__ W1,
    u16* __restrict__ ws)
{
  int blk = blockIdx.x;     // 72 Wf, 72 Wb, 72 W0, 32 W1
  int n = threadIdx.x;
  const float* src; u16* dst; int kb; int mode;
  if (blk < 72)       { src=Wf; dst=ws+OWF/2; kb=blk;     mode=0; }
  else if (blk < 144) { src=Wb; dst=ws+OWB/2; kb=blk-72;  mode=0; }
  else if (blk < 216) { src=W0; dst=ws+OW0/2; kb=blk-144; mode=1; }
  else                { src=W1; dst=ws+OW1/2; kb=blk-216; mode=2; }
  u16 pk[8];
  #pragma unroll
  for (int j=0;j<8;j++) {
    int k = kb*8+j;
    int sr;
    if (mode==0)      sr = (k<507)? k : (k<564)? k+100 : -1;  // skip tgt rows 507..606 (folded)
    else if (mode==1) sr = (k<555)? k : -1;
    else              sr = k;
    float v = (sr>=0)? src[sr*256+n] : 0.f;
    pk[j] = f2b(v);
  }
  *(uint4*)(dst + (kb*256+n)*8) = *(uint4*)pk;
}

// Fold per-batch target block (K rows 507..606) + bias into C-init vectors (f32)
__global__ __launch_bounds__(256) void prep_tgt(
    const int* __restrict__ target, const int* __restrict__ widx,
    const float* __restrict__ Wf, const float* __restrict__ bfv,
    const float* __restrict__ Wb, const float* __restrict__ bbv,
    float* __restrict__ wsf)
{
  int b = blockIdx.x, n = threadIdx.x;
  __shared__ float tval[100]; __shared__ int tg[10];
  if (n<10) tg[n]=target[b*10+n];
  __syncthreads();
  if (n<100){ int w=widx[n]; float v=1.f;
    #pragma unroll
    for(int i=0;i<10;i++) if(tg[i]==w) v=0.f;
    tval[n]=v; }
  __syncthreads();
  float aF=bfv[n], aB=bbv[n];
  for(int k=0;k<100;k++){ float v=tval[k];
    aF=fmaf(v,Wf[(507+k)*256+n],aF); aB=fmaf(v,Wb[(507+k)*256+n],aB); }
  wsf[OTF/4 + b*256+n]=aF; wsf[OTB/4 + b*256+n]=aB;
}

__global__ __launch_bounds__(256) void gemm_kernel(
    const int* __restrict__ code, const float* __restrict__ others,
    const int* __restrict__ length,
    const float* __restrict__ b0, const float* __restrict__ b1,
    const u16* __restrict__ wsu, const float* __restrict__ wsf,
    float* __restrict__ out)
{
  const int tile = blockIdx.x;   // 0..197 (M-tiles of 64; 198*64 = 12672 exact)
  const int strm = blockIdx.y;   // 0 fwd, 1 bwd, 2 mlp
  const int tid = threadIdx.x;
  const int wv = tid>>6, lane = tid&63, q = lane>>4, c = lane&15;
  const int colbase = wv*64 + c; // N-split: wave owns cols [wv*64, wv*64+64)

  __shared__ u16 lB[16384];      // 64K x 256N packed bf16 (32 KB)
  __shared__ u16 lA[4096];       // 64K x 64M packed bf16 (8 KB)
  __shared__ int ccf[2560];      // 64 rows x 40 codes
  __shared__ int rowB[64], rowT[64], rowS[64], rowS2[64], rowL[64];
  __shared__ float rpart[4][64];

  if (tid < 64) {
    int m = tile*64 + tid;
    int b = m/198, t = m - b*198;
    int L = length[b];
    int s, s2 = 0;
    if (strm==0) s = t;
    else if (strm==1){ s = (t<L)? (L-1-t) : t;
                       s2 = (t==0)? -1 : (((t-1)<L)? (L-t) : (t-1)); }
    else s = t+1;
    rowB[tid]=b; rowT[tid]=t; rowS[tid]=s; rowS2[tid]=s2; rowL[tid]=L;
  }
  __syncthreads();
  for (int idx=tid; idx<2560; idx+=256) {
    int r = idx/40, p = idx - r*40;
    ccf[idx] = code[(rowB[r]*TMAX + rowS[r])*PC + p];
  }

  // ---- C init: fwd/bwd from folded tgt+bias (f32), mlp from b0 ----
  f32x4 acc[4][4];
  if (strm < 2) {
    const float* tg = wsf + ((strm==0)? OTF/4 : OTB/4);
    #pragma unroll
    for (int mt=0; mt<4; mt++)
      #pragma unroll
      for (int reg=0; reg<4; reg++) {
        int rl = mt*16 + q*4 + reg;
        const float* tr = tg + rowB[rl]*256;
        #pragma unroll
        for (int nt=0; nt<4; nt++) acc[mt][nt][reg] = tr[colbase + nt*16];
      }
  } else {
    #pragma unroll
    for (int nt=0; nt<4; nt++){ float v = b0[colbase + nt*16];
      #pragma unroll
      for (int mt=0; mt<4; mt++)
        #pragma unroll
        for (int reg=0; reg<4; reg++) acc[mt][nt][reg]=v; }
  }

  const u16* Wpk = wsu + ((strm==0)? OWF/2 : (strm==1)? OWB/2 : OW0/2);
  for (int kt=0; kt<NKT; kt++) {
    __syncthreads();                       // prior compute done with lA/lB
    {                                      // stage B tile (contiguous 32 KB)
      const uint4* g = (const uint4*)(Wpk + kt*16384);
      uint4* l = (uint4*)lB;
      #pragma unroll
      for (int it=0; it<8; it++) l[it*256+tid] = g[it*256+tid];
    }
    {                                      // zero A tile
      uint4 z = {0,0,0,0};
      uint4* l = (uint4*)lA;
      l[tid] = z; l[256+tid] = z;
    }
    __syncthreads();                       // zeros visible before scatter
    const int k0 = kt*64;
    if (kt < 8) {                          // one-hot scatter (codes < 507); dup writes idempotent
      for (int idx=tid; idx<2560; idx+=256) {
        unsigned d = (unsigned)(ccf[idx] - k0);
        if (d < 64u) {
          int r = idx/40;
          lA[((d>>3)*64 + r)*8 + (d&7)] = 0x3F80;  // bf16 1.0
        }
      }
    }
    if (kt >= 7) {                         // dense tail dims k' = 507+j
      if (strm < 2) {
        for (int idx=tid; idx<64*57; idx+=256) {
          int r = idx/57, j = idx - r*57;
          unsigned d = (unsigned)(507 + j - k0);
          if (d < 64u) {
            int col = (j<27)? j : (j<47)? 37+(j-27) : 27+(j-47);
            int sr = (strm==1 && j>=47)? rowS2[r] : rowS[r];
            if (sr >= 0) {
              float v = others[(rowB[r]*TMAX + sr)*DOTH + col];
              lA[((d>>3)*64 + r)*8 + (d&7)] = f2b(v);
            }
          }
        }
      } else {
        for (int idx=tid; idx<64*48; idx+=256) {
          int r = idx/48, j = idx - r*48;
          unsigned d = (unsigned)(507 + j - k0);
          if (d < 64u) {
            int t = rowT[r], srow, col;
            if (j<20)      { srow=t+1; col=37+j; }
            else if (j<30) { srow=t+1; col=27+(j-20); }
            else if (j<40) { srow=t+2; col=27+(j-30); }
            else           { srow=t+1; col=19+(j-40); }
            float v = others[(rowB[r]*TMAX + srow)*DOTH + col];
            lA[((d>>3)*64 + r)*8 + (d&7)] = f2b(v);
          }
        }
      }
    }
    __syncthreads();                       // A/B visible; vmcnt drained by barrier
    #pragma unroll
    for (int s=0; s<2; s++) {
      int akb = s*4 + q;
      short8 af[4], bf8[4];
      #pragma unroll
      for (int mt=0; mt<4; mt++) af[mt]  = *(const short8*)&lA[(akb*64  + mt*16 + c)*8];
      #pragma unroll
      for (int nt=0; nt<4; nt++) bf8[nt] = *(const short8*)&lB[(akb*256 + colbase + nt*16)*8];
      #pragma unroll
      for (int mt=0; mt<4; mt++)
        #pragma unroll
        for (int nt=0; nt<4; nt++)
          acc[mt][nt] = __builtin_amdgcn_mfma_f32_16x16x32_bf16(af[mt], bf8[nt], acc[mt][nt], 0,0,0);
    }
  }

  if (strm < 2) {
    float* o = out + ((strm==0)? FWD_OFF : BWD_OFF);
    #pragma unroll
    for (int mt=0; mt<4; mt++)
      #pragma unroll
      for (int reg=0; reg<4; reg++) {
        int rl = mt*16 + q*4 + reg;
        float* orow = o + (rowB[rl]*TOUT + rowT[rl])*256 + colbase;
        #pragma unroll
        for (int nt=0; nt<4; nt++) orow[nt*16] = acc[mt][nt][reg];
      }
  } else {
    // ---- MLP: relu(h) -> lB as packed A2; GEMM2 vs W1 (B frags from L2); l2norm ----
    __syncthreads();                       // everyone done reading lB
    #pragma unroll
    for (int mt=0; mt<4; mt++)
      #pragma unroll
      for (int reg=0; reg<4; reg++) {
        int rl = mt*16 + q*4 + reg;
        #pragma unroll
        for (int nt=0; nt<4; nt++) {
          int col = colbase + nt*16;
          lB[((col>>3)*64 + rl)*8 + (col&7)] = f2b(fmaxf(acc[mt][nt][reg], 0.f));
        }
      }
    __syncthreads();
    f32x4 a2[4][4];
    #pragma unroll
    for (int nt=0; nt<4; nt++){ float v = b1[colbase + nt*16];
      #pragma unroll
      for (int mt=0; mt<4; mt++)
        #pragma unroll
        for (int reg=0; reg<4; reg++) a2[mt][nt][reg]=v; }
    const u16* W1p = wsu + OW1/2;
    #pragma unroll
    for (int s=0; s<8; s++) {
      int akb = s*4 + q;
      short8 af[4], bf8[4];
      #pragma unroll
      for (int mt=0; mt<4; mt++) af[mt]  = *(const short8*)&lB[(akb*64 + mt*16 + c)*8];
      #pragma unroll
      for (int nt=0; nt<4; nt++) bf8[nt] = *(const short8*)(W1p + (akb*256 + colbase + nt*16)*8);
      #pragma unroll
      for (int mt=0; mt<4; mt++)
        #pragma unroll
        for (int nt=0; nt<4; nt++)
          a2[mt][nt] = __builtin_amdgcn_mfma_f32_16x16x32_bf16(af[mt], bf8[nt], a2[mt][nt], 0,0,0);
    }
    // row-wise sum of squares: reduce 4 nt in-lane, 16 c-lanes via shfl, 4 waves via LDS
    #pragma unroll
    for (int mt=0; mt<4; mt++)
      #pragma unroll
      for (int reg=0; reg<4; reg++) {
        int rl = mt*16 + q*4 + reg;
        float ss = 0.f;
        #pragma unroll
        for (int nt=0; nt<4; nt++){ float v=a2[mt][nt][reg]; ss = fmaf(v,v,ss); }
        ss += __shfl_xor(ss, 1, 64); ss += __shfl_xor(ss, 2, 64);
        ss += __shfl_xor(ss, 4, 64); ss += __shfl_xor(ss, 8, 64);
        if (c==0) rpart[wv][rl] = ss;
      }
    __syncthreads();
    #pragma unroll
    for (int mt=0; mt<4; mt++)
      #pragma unroll
      for (int reg=0; reg<4; reg++) {
        int rl = mt*16 + q*4 + reg;
        float s = rpart[0][rl]+rpart[1][rl]+rpart[2][rl]+rpart[3][rl];
        float inv = (s>0.f)? (1.0f/sqrtf(s)) : 0.f;
        int t = rowT[rl];
        if (t >= rowL[rl]-2) inv = 0.f;    // mask
        float* orow = out + FV_OFF + (rowB[rl]*TOUT + t)*256 + colbase;
        #pragma unroll
        for (int nt=0; nt<4; nt++) orow[nt*16] = a2[mt][nt][reg]*inv;
      }
  }
}

extern "C" void kernel_launch(void* const* d_in, const int* in_sizes, int n_in,
                              void* d_out, int out_size, void* d_ws, size_t ws_size,
                              hipStream_t stream) {
  const int*   code    = (const int*)d_in[0];
  const float* others  = (const float*)d_in[1];
  const int*   length  = (const int*)d_in[2];
  const int*   target  = (const int*)d_in[3];
  const int*   widx    = (const int*)d_in[4];
  const float* Wf      = (const float*)d_in[5];
  const float* bfv     = (const float*)d_in[6];
  const float* Wb      = (const float*)d_in[7];
  const float* bbv     = (const float*)d_in[8];
  const float* W0      = (const float*)d_in[9];
  const float* b0v     = (const float*)d_in[10];
  const float* W1      = (const float*)d_in[11];
  const float* b1v     = (const float*)d_in[12];

  u16*   wsu = (u16*)d_ws;
  float* wsf = (float*)d_ws;
  float* out = (float*)d_out;

  prep_pack<<<dim3(248), dim3(256), 0, stream>>>(Wf, Wb, W0, W1, wsu);
  prep_tgt<<<dim3(64),  dim3(256), 0, stream>>>(target, widx, Wf, bfv, Wb, bbv, wsf);
  gemm_kernel<<<dim3(198,3), dim3(256), 0, stream>>>(code, others, length,
      b0v, b1v, wsu, wsf, out);
}

// Round 6
// 152.265 us; speedup vs baseline: 1.5961x; 1.1564x over previous
//
#include <hip/hip_runtime.h>
#include <hip/hip_bf16.h>

typedef unsigned short u16;
typedef __attribute__((ext_vector_type(8))) short short8;
typedef __attribute__((ext_vector_type(4))) float f32x4;

#define TMAX 200
#define TOUT 198
#define PC 40
#define DOTH 57
#define NKT 9            // K tiles of 64 (K padded to 576); dense dims k=0..56, codes k=57+c
#define FWD_OFF 0
#define BWD_OFF 3244032
#define FV_OFF  6488064
// ws byte offsets: packed bf16 weights + f32 tgt folds
#define OWF 0
#define OWB 294912
#define OW0 589824
#define OW1 884736
#define OTF 1015808
#define OTB 1081344

__device__ __forceinline__ u16 f2b(float v) {
  __hip_bfloat16 h = __float2bfloat16(v);
  return *(u16*)&h;
}

// One prep launch: blocks 0..247 pack weights to MFMA-frag layout
// dst[((k>>3)*256 + n)*8 + (k&7)]; blocks 248..311 fold tgt+bias per batch.
// Packed K order (mode 0, Wf/Wb): k 0..56 = dense (orig rows 607+k),
// k 57..563 = code one-hots (orig rows k-57), rest 0.
// mode 1 (W0): k 0..47 = dense (orig 507+k), 48..56 = 0, 57..563 = codes.
__global__ __launch_bounds__(256) void prep_kernel(
    const int* __restrict__ target, const int* __restrict__ widx,
    const float* __restrict__ Wf, const float* __restrict__ bfv,
    const float* __restrict__ Wb, const float* __restrict__ bbv,
    const float* __restrict__ W0, const float* __restrict__ W1,
    u16* __restrict__ wsu, float* __restrict__ wsf)
{
  int blk = blockIdx.x, n = threadIdx.x;
  if (blk < 248) {
    const float* src; u16* dst; int kb; int mode;
    if (blk < 72)       { src=Wf; dst=wsu+OWF/2; kb=blk;     mode=0; }
    else if (blk < 144) { src=Wb; dst=wsu+OWB/2; kb=blk-72;  mode=0; }
    else if (blk < 216) { src=W0; dst=wsu+OW0/2; kb=blk-144; mode=1; }
    else                { src=W1; dst=wsu+OW1/2; kb=blk-216; mode=2; }
    u16 pk[8];
    #pragma unroll
    for (int j=0;j<8;j++) {
      int k = kb*8+j;
      int sr;
      if (mode==0)      sr = (k<57)? 607+k : (k<564)? k-57 : -1;
      else if (mode==1) sr = (k<48)? 507+k : (k<57)? -1 : (k<564)? k-57 : -1;
      else              sr = k;
      float v = (sr>=0)? src[sr*256+n] : 0.f;
      pk[j] = f2b(v);
    }
    *(uint4*)(dst + (kb*256+n)*8) = *(uint4*)pk;
  } else {
    int b = blk - 248;
    __shared__ float tval[100]; __shared__ int tg[10];
    if (n<10) tg[n]=target[b*10+n];
    __syncthreads();
    if (n<100){ int w=widx[n]; float v=1.f;
      #pragma unroll
      for(int i=0;i<10;i++) if(tg[i]==w) v=0.f;
      tval[n]=v; }
    __syncthreads();
    float aF=bfv[n], aB=bbv[n];
    for(int k=0;k<100;k++){ float v=tval[k];
      aF=fmaf(v,Wf[(507+k)*256+n],aF); aB=fmaf(v,Wb[(507+k)*256+n],aB); }
    wsf[OTF/4 + b*256+n]=aF; wsf[OTB/4 + b*256+n]=aB;
  }
}

__global__ __launch_bounds__(256) void gemm_kernel(
    const int* __restrict__ code, const float* __restrict__ others,
    const int* __restrict__ length,
    const float* __restrict__ b0, const float* __restrict__ b1,
    const u16* __restrict__ wsu, const float* __restrict__ wsf,
    float* __restrict__ out)
{
  const int tile = blockIdx.x;   // 0..197 (M-tiles of 64)
  const int strm = blockIdx.y;   // 0 fwd, 1 bwd, 2 mlp
  const int tid = threadIdx.x;
  const int wv = tid>>6, lane = tid&63, q = lane>>4, c = lane&15;
  const int colbase = wv*64 + c;

  __shared__ u16 lA[2][4096];    // double-buffered 64K x 64M bf16 tiles (2x8 KB)
  __shared__ int rowB[64], rowT[64], rowS[64], rowS2[64], rowL[64];
  __shared__ float rpart[4][64];

  if (tid < 64) {
    int m = tile*64 + tid;
    int b = m/198, t = m - b*198;
    int L = length[b];
    int s, s2 = 0;
    if (strm==0) s = t;
    else if (strm==1){ s = (t<L)? (L-1-t) : t;
                       s2 = (t==0)? -1 : (((t-1)<L)? (L-t) : (t-1)); }
    else s = t+1;
    rowB[tid]=b; rowT[tid]=t; rowS[tid]=s; rowS2[tid]=s2; rowL[tid]=L;
  }
  __syncthreads();

  // code scatter positions (k = 57+code) + row bases -> registers
  int myp[10], myr[10];
  #pragma unroll
  for (int it=0; it<10; it++) {
    int idx = tid + it*256;
    int r = idx/40, p = idx - r*40;
    myr[it] = r*8;
    myp[it] = 57 + code[(rowB[r]*TMAX + rowS[r])*PC + p];
  }

  // dense-dim prefetch (registers; consumed in kt0)
  float dv[15];
  if (strm < 2) {
    #pragma unroll
    for (int it=0; it<15; it++) {
      int idx = tid + it*256;
      float v = 0.f;
      if (idx < 64*57) {
        int r = idx/57, j = idx - r*57;
        int col = (j<27)? j : (j<47)? 37+(j-27) : 27+(j-47);
        int sr = (strm==1 && j>=47)? rowS2[r] : rowS[r];
        if (sr >= 0) v = others[(rowB[r]*TMAX + sr)*DOTH + col];
      }
      dv[it] = v;
    }
  } else {
    #pragma unroll
    for (int it=0; it<12; it++) {
      int idx = tid + it*256;
      int r = idx/48, j = idx - r*48;
      int t = rowT[r], srow, col;
      if (j<20)      { srow=t+1; col=37+j; }
      else if (j<30) { srow=t+1; col=27+(j-20); }
      else if (j<40) { srow=t+2; col=27+(j-30); }
      else           { srow=t+1; col=19+(j-40); }
      dv[it] = others[(rowB[r]*TMAX + srow)*DOTH + col];
    }
  }

  // ---- C init ----
  f32x4 acc[4][4];
  if (strm < 2) {
    const float* tg = wsf + ((strm==0)? OTF/4 : OTB/4);
    #pragma unroll
    for (int mt=0; mt<4; mt++)
      #pragma unroll
      for (int reg=0; reg<4; reg++) {
        int rl = mt*16 + q*4 + reg;
        const float* tr = tg + rowB[rl]*256;
        #pragma unroll
        for (int nt=0; nt<4; nt++) acc[mt][nt][reg] = tr[colbase + nt*16];
      }
  } else {
    #pragma unroll
    for (int nt=0; nt<4; nt++){ float v = b0[colbase + nt*16];
      #pragma unroll
      for (int mt=0; mt<4; mt++)
        #pragma unroll
        for (int reg=0; reg<4; reg++) acc[mt][nt][reg]=v; }
  }

  const u16* Wpk = wsu + ((strm==0)? OWF/2 : (strm==1)? OWB/2 : OW0/2);
  for (int kt=0; kt<NKT; kt++) {
    u16* A = lA[kt&1];
    // zero this A buffer (safe: waves reading other buffer)
    { uint4 z = {0,0,0,0};
      ((uint4*)A)[tid] = z; ((uint4*)A)[256+tid] = z; }
    __syncthreads();
    const int k0 = kt*64;
    #pragma unroll
    for (int it=0; it<10; it++) {
      unsigned d = (unsigned)(myp[it] - k0);
      if (d < 64u) A[(d>>3)*512 + myr[it] + (d&7)] = 0x3F80;  // bf16 1.0
    }
    if (kt == 0) {
      if (strm < 2) {
        #pragma unroll
        for (int it=0; it<15; it++) {
          int idx = tid + it*256;
          if (idx < 64*57) {
            int r = idx/57, j = idx - r*57;
            A[(j>>3)*512 + r*8 + (j&7)] = f2b(dv[it]);
          }
        }
      } else {
        #pragma unroll
        for (int it=0; it<12; it++) {
          int idx = tid + it*256;
          int r = idx/48, j = idx - r*48;
          A[(j>>3)*512 + r*8 + (j&7)] = f2b(dv[it]);
        }
      }
    }
    __syncthreads();
    #pragma unroll
    for (int s=0; s<2; s++) {
      int akb = s*4 + q;
      const u16* gB = Wpk + ((kt*8 + akb)*256 + colbase)*8;
      short8 af[4], bf[4];
      #pragma unroll
      for (int nt=0; nt<4; nt++) bf[nt] = *(const short8*)(gB + nt*16*8);
      #pragma unroll
      for (int mt=0; mt<4; mt++) af[mt] = *(const short8*)&A[(akb*64 + mt*16 + c)*8];
      #pragma unroll
      for (int mt=0; mt<4; mt++)
        #pragma unroll
        for (int nt=0; nt<4; nt++)
          acc[mt][nt] = __builtin_amdgcn_mfma_f32_16x16x32_bf16(af[mt], bf[nt], acc[mt][nt], 0,0,0);
    }
  }
  __syncthreads();   // all lA reads done (uniform across block)

  if (strm < 2) {
    float* o = out + ((strm==0)? FWD_OFF : BWD_OFF);
    #pragma unroll
    for (int mt=0; mt<4; mt++)
      #pragma unroll
      for (int reg=0; reg<4; reg++) {
        int rl = mt*16 + q*4 + reg;
        float* orow = o + (rowB[rl]*TOUT + rowT[rl])*256 + colbase;
        #pragma unroll
        for (int nt=0; nt<4; nt++) orow[nt*16] = acc[mt][nt][reg];
      }
  } else {
    // ---- GEMM2: relu(h) ping-pong chunks through lA; W1 frags from L2 ----
    // wave wv owns h cols [wv*64, wv*64+64) == K-chunk wv of GEMM2
    if (wv == 0) {
      #pragma unroll
      for (int mt=0; mt<4; mt++)
        #pragma unroll
        for (int reg=0; reg<4; reg++) {
          int rl = mt*16 + q*4 + reg;
          #pragma unroll
          for (int nt=0; nt<4; nt++) {
            int kl = c + nt*16;
            lA[0][(kl>>3)*512 + rl*8 + (kl&7)] = f2b(fmaxf(acc[mt][nt][reg], 0.f));
          }
        }
    }
    __syncthreads();
    f32x4 a2[4][4];
    #pragma unroll
    for (int nt=0; nt<4; nt++){ float v = b1[colbase + nt*16];
      #pragma unroll
      for (int mt=0; mt<4; mt++)
        #pragma unroll
        for (int reg=0; reg<4; reg++) a2[mt][nt][reg]=v; }
    const u16* W1p = wsu + OW1/2;
    for (int kt2=0; kt2<4; kt2++) {
      if (wv == kt2+1) {   // write next chunk into other buffer (wv<=3 guards kt2=3)
        u16* B2 = lA[(kt2+1)&1];
        #pragma unroll
        for (int mt=0; mt<4; mt++)
          #pragma unroll
          for (int reg=0; reg<4; reg++) {
            int rl = mt*16 + q*4 + reg;
            #pragma unroll
            for (int nt=0; nt<4; nt++) {
              int kl = c + nt*16;
              B2[(kl>>3)*512 + rl*8 + (kl&7)] = f2b(fmaxf(acc[mt][nt][reg], 0.f));
            }
          }
      }
      const u16* A2 = lA[kt2&1];
      #pragma unroll
      for (int s=0; s<2; s++) {
        int akb = s*4 + q;
        const u16* gB = W1p + ((kt2*8 + akb)*256 + colbase)*8;
        short8 af[4], bf[4];
        #pragma unroll
        for (int nt=0; nt<4; nt++) bf[nt] = *(const short8*)(gB + nt*16*8);
        #pragma unroll
        for (int mt=0; mt<4; mt++) af[mt] = *(const short8*)&A2[(akb*64 + mt*16 + c)*8];
        #pragma unroll
        for (int mt=0; mt<4; mt++)
          #pragma unroll
          for (int nt=0; nt<4; nt++)
            a2[mt][nt] = __builtin_amdgcn_mfma_f32_16x16x32_bf16(af[mt], bf[nt], a2[mt][nt], 0,0,0);
      }
      __syncthreads();
    }
    // row-wise sum of squares -> l2norm + mask
    #pragma unroll
    for (int mt=0; mt<4; mt++)
      #pragma unroll
      for (int reg=0; reg<4; reg++) {
        int rl = mt*16 + q*4 + reg;
        float ss = 0.f;
        #pragma unroll
        for (int nt=0; nt<4; nt++){ float v=a2[mt][nt][reg]; ss = fmaf(v,v,ss); }
        ss += __shfl_xor(ss, 1, 64); ss += __shfl_xor(ss, 2, 64);
        ss += __shfl_xor(ss, 4, 64); ss += __shfl_xor(ss, 8, 64);
        if (c==0) rpart[wv][rl] = ss;
      }
    __syncthreads();
    #pragma unroll
    for (int mt=0; mt<4; mt++)
      #pragma unroll
      for (int reg=0; reg<4; reg++) {
        int rl = mt*16 + q*4 + reg;
        float s = rpart[0][rl]+rpart[1][rl]+rpart[2][rl]+rpart[3][rl];
        float inv = (s>0.f)? (1.0f/sqrtf(s)) : 0.f;
        int t = rowT[rl];
        if (t >= rowL[rl]-2) inv = 0.f;
        float* orow = out + FV_OFF + (rowB[rl]*TOUT + t)*256 + colbase;
        #pragma unroll
        for (int nt=0; nt<4; nt++) orow[nt*16] = a2[mt][nt][reg]*inv;
      }
  }
}

extern "C" void kernel_launch(void* const* d_in, const int* in_sizes, int n_in,
                              void* d_out, int out_size, void* d_ws, size_t ws_size,
                              hipStream_t stream) {
  const int*   code    = (const int*)d_in[0];
  const float* others  = (const float*)d_in[1];
  const int*   length  = (const int*)d_in[2];
  const int*   target  = (const int*)d_in[3];
  const int*   widx    = (const int*)d_in[4];
  const float* Wf      = (const float*)d_in[5];
  const float* bfv     = (const float*)d_in[6];
  const float* Wb      = (const float*)d_in[7];
  const float* bbv     = (const float*)d_in[8];
  const float* W0      = (const float*)d_in[9];
  const float* b0v     = (const float*)d_in[10];
  const float* W1      = (const float*)d_in[11];
  const float* b1v     = (const float*)d_in[12];

  u16*   wsu = (u16*)d_ws;
  float* wsf = (float*)d_ws;
  float* out = (float*)d_out;

  prep_kernel<<<dim3(312), dim3(256), 0, stream>>>(target, widx, Wf, bfv, Wb, bbv, W0, W1, wsu, wsf);
  gemm_kernel<<<dim3(198,3), dim3(256), 0, stream>>>(code, others, length,
      b0v, b1v, wsu, wsf, out);
}

// Round 7
// 120.605 us; speedup vs baseline: 2.0151x; 1.2625x over previous
//
#include <hip/hip_runtime.h>
#include <hip/hip_bf16.h>

typedef unsigned short u16;
typedef __attribute__((ext_vector_type(8))) short short8;
typedef __attribute__((ext_vector_type(4))) float f32x4;

#define TMAX 200
#define TOUT 198
#define PC 40
#define DOTH 57
#define NKT 9            // K tiles of 64 (K padded to 576); dense dims k=0..56, codes k=57+c
#define FWD_OFF 0
#define BWD_OFF 3244032
#define FV_OFF  6488064
// ws byte offsets: packed bf16 weights + f32 tgt folds
#define OWF 0
#define OWB 294912
#define OW0 589824
#define OW1 884736
#define OTF 1015808
#define OTB 1081344

__device__ __forceinline__ u16 f2b(float v) {
  __hip_bfloat16 h = __float2bfloat16(v);
  return *(u16*)&h;
}

// One prep launch: blocks 0..247 pack weights to MFMA-frag layout
// dst[((k>>3)*256 + n)*8 + (k&7)]; blocks 248..311 fold tgt+bias per batch.
__global__ __launch_bounds__(256) void prep_kernel(
    const int* __restrict__ target, const int* __restrict__ widx,
    const float* __restrict__ Wf, const float* __restrict__ bfv,
    const float* __restrict__ Wb, const float* __restrict__ bbv,
    const float* __restrict__ W0, const float* __restrict__ W1,
    u16* __restrict__ wsu, float* __restrict__ wsf)
{
  int blk = blockIdx.x, n = threadIdx.x;
  if (blk < 248) {
    const float* src; u16* dst; int kb; int mode;
    if (blk < 72)       { src=Wf; dst=wsu+OWF/2; kb=blk;     mode=0; }
    else if (blk < 144) { src=Wb; dst=wsu+OWB/2; kb=blk-72;  mode=0; }
    else if (blk < 216) { src=W0; dst=wsu+OW0/2; kb=blk-144; mode=1; }
    else                { src=W1; dst=wsu+OW1/2; kb=blk-216; mode=2; }
    u16 pk[8];
    #pragma unroll
    for (int j=0;j<8;j++) {
      int k = kb*8+j;
      int sr;
      if (mode==0)      sr = (k<57)? 607+k : (k<564)? k-57 : -1;
      else if (mode==1) sr = (k<48)? 507+k : (k<57)? -1 : (k<564)? k-57 : -1;
      else              sr = k;
      float v = (sr>=0)? src[sr*256+n] : 0.f;
      pk[j] = f2b(v);
    }
    *(uint4*)(dst + (kb*256+n)*8) = *(uint4*)pk;
  } else {
    int b = blk - 248;
    __shared__ float tval[100]; __shared__ int tg[10];
    if (n<10) tg[n]=target[b*10+n];
    __syncthreads();
    if (n<100){ int w=widx[n]; float v=1.f;
      #pragma unroll
      for(int i=0;i<10;i++) if(tg[i]==w) v=0.f;
      tval[n]=v; }
    __syncthreads();
    float aF=bfv[n], aB=bbv[n];
    for(int k=0;k<100;k++){ float v=tval[k];
      aF=fmaf(v,Wf[(507+k)*256+n],aF); aB=fmaf(v,Wb[(507+k)*256+n],aB); }
    wsf[OTF/4 + b*256+n]=aF; wsf[OTB/4 + b*256+n]=aB;
  }
}

__global__ __launch_bounds__(256) void gemm_kernel(
    const int* __restrict__ code, const float* __restrict__ others,
    const int* __restrict__ length,
    const float* __restrict__ b0, const float* __restrict__ b1,
    const u16* __restrict__ wsu, const float* __restrict__ wsf,
    float* __restrict__ out)
{
  const int tile = blockIdx.x;   // 0..395 (M-tiles of 32; 396*32 = 12672)
  const int strm = blockIdx.y;   // 0 fwd, 1 bwd, 2 mlp
  const int tid = threadIdx.x;
  const int wv = tid>>6, lane = tid&63, q = lane>>4, c = lane&15;
  const int colbase = wv*64 + c;

  __shared__ u16 lA[3][2048];    // triple-buffered 64K x 32M bf16 tiles (3x4 KB)
  __shared__ int rowB[32], rowT[32], rowS[32], rowS2[32], rowL[32];
  __shared__ float rpart[4][32];

  if (tid < 32) {
    int m = tile*32 + tid;
    int b = m/198, t = m - b*198;
    int L = length[b];
    int s, s2 = 0;
    if (strm==0) s = t;
    else if (strm==1){ s = (t<L)? (L-1-t) : t;
                       s2 = (t==0)? -1 : (((t-1)<L)? (L-t) : (t-1)); }
    else s = t+1;
    rowB[tid]=b; rowT[tid]=t; rowS[tid]=s; rowS2[tid]=s2; rowL[tid]=L;
  }
  __syncthreads();

  // code scatter positions (k = 57+code) + row bases -> registers (32*40=1280 = 5/thread)
  int myp[5], myr[5];
  #pragma unroll
  for (int it=0; it<5; it++) {
    int idx = tid + it*256;
    int r = idx/40, p = idx - r*40;
    myr[it] = r*8;
    myp[it] = 57 + code[(rowB[r]*TMAX + rowS[r])*PC + p];
  }

  // dense-dim prefetch (registers; consumed in prologue)
  float dv[8];
  if (strm < 2) {
    #pragma unroll
    for (int it=0; it<8; it++) {
      int idx = tid + it*256;
      float v = 0.f;
      if (idx < 32*57) {
        int r = idx/57, j = idx - r*57;
        int col = (j<27)? j : (j<47)? 37+(j-27) : 27+(j-47);
        int sr = (strm==1 && j>=47)? rowS2[r] : rowS[r];
        if (sr >= 0) v = others[(rowB[r]*TMAX + sr)*DOTH + col];
      }
      dv[it] = v;
    }
  } else {
    #pragma unroll
    for (int it=0; it<6; it++) {
      int idx = tid + it*256;
      int r = idx/48, j = idx - r*48;
      int t = rowT[r], srow, col;
      if (j<20)      { srow=t+1; col=37+j; }
      else if (j<30) { srow=t+1; col=27+(j-20); }
      else if (j<40) { srow=t+2; col=27+(j-30); }
      else           { srow=t+1; col=19+(j-40); }
      dv[it] = others[(rowB[r]*TMAX + srow)*DOTH + col];
    }
  }

  // ---- C init ----
  f32x4 acc[2][4];
  if (strm < 2) {
    const float* tg = wsf + ((strm==0)? OTF/4 : OTB/4);
    #pragma unroll
    for (int mt=0; mt<2; mt++)
      #pragma unroll
      for (int reg=0; reg<4; reg++) {
        int rl = mt*16 + q*4 + reg;
        const float* tr = tg + rowB[rl]*256;
        #pragma unroll
        for (int nt=0; nt<4; nt++) acc[mt][nt][reg] = tr[colbase + nt*16];
      }
  } else {
    #pragma unroll
    for (int nt=0; nt<4; nt++){ float v = b0[colbase + nt*16];
      #pragma unroll
      for (int mt=0; mt<2; mt++)
        #pragma unroll
        for (int reg=0; reg<4; reg++) acc[mt][nt][reg]=v; }
  }

  // ---- prologue: zero buf0+buf1, scatter window 0 (+dense) into buf0 ----
  { uint4 z = {0,0,0,0};
    ((uint4*)lA[0])[tid] = z; ((uint4*)lA[1])[tid] = z; }
  __syncthreads();
  #pragma unroll
  for (int it=0; it<5; it++) {
    unsigned d = (unsigned)(myp[it]);
    if (d < 64u) lA[0][(d>>3)*256 + myr[it] + (d&7)] = 0x3F80;
  }
  if (strm < 2) {
    #pragma unroll
    for (int it=0; it<8; it++) {
      int idx = tid + it*256;
      if (idx < 32*57) {
        int r = idx/57, j = idx - r*57;
        lA[0][(j>>3)*256 + r*8 + (j&7)] = f2b(dv[it]);
      }
    }
  } else {
    #pragma unroll
    for (int it=0; it<6; it++) {
      int idx = tid + it*256;
      int r = idx/48, j = idx - r*48;
      lA[0][(j>>3)*256 + r*8 + (j&7)] = f2b(dv[it]);
    }
  }
  __syncthreads();

  const u16* Wpk = wsu + ((strm==0)? OWF/2 : (strm==1)? OWB/2 : OW0/2);
  for (int kt=0; kt<NKT; kt++) {
    const u16* A = lA[kt%3];
    // issue B-frag loads first (independent of LDS state)
    const u16* gB0 = Wpk + ((kt*8 + q    )*256 + colbase)*8;
    const u16* gB1 = Wpk + ((kt*8 + 4 + q)*256 + colbase)*8;
    short8 bf0[4], bf1[4];
    #pragma unroll
    for (int nt=0; nt<4; nt++) bf0[nt] = *(const short8*)(gB0 + nt*16*8);
    #pragma unroll
    for (int nt=0; nt<4; nt++) bf1[nt] = *(const short8*)(gB1 + nt*16*8);
    // scatter window kt+1 into buf[(kt+1)%3] (zeroed at iter kt-1)
    if (kt < 8) {
      u16* nb = lA[(kt+1)%3];
      const int k0n = (kt+1)*64;
      #pragma unroll
      for (int it=0; it<5; it++) {
        unsigned d = (unsigned)(myp[it] - k0n);
        if (d < 64u) nb[(d>>3)*256 + myr[it] + (d&7)] = 0x3F80;
      }
    }
    // zero buf[(kt+2)%3] (last read at iter kt-1)
    if (kt < 7) {
      uint4 z = {0,0,0,0};
      ((uint4*)lA[(kt+2)%3])[tid] = z;
    }
    // MFMA
    short8 af0[2], af1[2];
    #pragma unroll
    for (int mt=0; mt<2; mt++) af0[mt] = *(const short8*)&A[(q    )*256 + (mt*16 + c)*8];
    #pragma unroll
    for (int mt=0; mt<2; mt++) af1[mt] = *(const short8*)&A[(4 + q)*256 + (mt*16 + c)*8];
    #pragma unroll
    for (int mt=0; mt<2; mt++)
      #pragma unroll
      for (int nt=0; nt<4; nt++)
        acc[mt][nt] = __builtin_amdgcn_mfma_f32_16x16x32_bf16(af0[mt], bf0[nt], acc[mt][nt], 0,0,0);
    #pragma unroll
    for (int mt=0; mt<2; mt++)
      #pragma unroll
      for (int nt=0; nt<4; nt++)
        acc[mt][nt] = __builtin_amdgcn_mfma_f32_16x16x32_bf16(af1[mt], bf1[nt], acc[mt][nt], 0,0,0);
    __syncthreads();
  }

  if (strm < 2) {
    float* o = out + ((strm==0)? FWD_OFF : BWD_OFF);
    #pragma unroll
    for (int mt=0; mt<2; mt++)
      #pragma unroll
      for (int reg=0; reg<4; reg++) {
        int rl = mt*16 + q*4 + reg;
        float* orow = o + (rowB[rl]*TOUT + rowT[rl])*256 + colbase;
        #pragma unroll
        for (int nt=0; nt<4; nt++) orow[nt*16] = acc[mt][nt][reg];
      }
  } else {
    // ---- GEMM2: relu(h) chunks ping-pong via lA[0]/lA[1]; W1 frags from L2 ----
    // wave wv owns h cols [wv*64, wv*64+64) == K-chunk wv of GEMM2
    if (wv == 0) {
      #pragma unroll
      for (int mt=0; mt<2; mt++)
        #pragma unroll
        for (int reg=0; reg<4; reg++) {
          int rl = mt*16 + q*4 + reg;
          #pragma unroll
          for (int nt=0; nt<4; nt++) {
            int kl = c + nt*16;
            lA[0][(kl>>3)*256 + rl*8 + (kl&7)] = f2b(fmaxf(acc[mt][nt][reg], 0.f));
          }
        }
    }
    __syncthreads();
    f32x4 a2[2][4];
    #pragma unroll
    for (int nt=0; nt<4; nt++){ float v = b1[colbase + nt*16];
      #pragma unroll
      for (int mt=0; mt<2; mt++)
        #pragma unroll
        for (int reg=0; reg<4; reg++) a2[mt][nt][reg]=v; }
    const u16* W1p = wsu + OW1/2;
    for (int kt2=0; kt2<4; kt2++) {
      if (wv == kt2+1) {   // write next chunk into other buffer
        u16* B2 = lA[(kt2+1)&1];
        #pragma unroll
        for (int mt=0; mt<2; mt++)
          #pragma unroll
          for (int reg=0; reg<4; reg++) {
            int rl = mt*16 + q*4 + reg;
            #pragma unroll
            for (int nt=0; nt<4; nt++) {
              int kl = c + nt*16;
              B2[(kl>>3)*256 + rl*8 + (kl&7)] = f2b(fmaxf(acc[mt][nt][reg], 0.f));
            }
          }
      }
      const u16* A2 = lA[kt2&1];
      #pragma unroll
      for (int s=0; s<2; s++) {
        int akb = s*4 + q;
        const u16* gB = W1p + ((kt2*8 + akb)*256 + colbase)*8;
        short8 af[2], bf[4];
        #pragma unroll
        for (int nt=0; nt<4; nt++) bf[nt] = *(const short8*)(gB + nt*16*8);
        #pragma unroll
        for (int mt=0; mt<2; mt++) af[mt] = *(const short8*)&A2[akb*256 + (mt*16 + c)*8];
        #pragma unroll
        for (int mt=0; mt<2; mt++)
          #pragma unroll
          for (int nt=0; nt<4; nt++)
            a2[mt][nt] = __builtin_amdgcn_mfma_f32_16x16x32_bf16(af[mt], bf[nt], a2[mt][nt], 0,0,0);
      }
      __syncthreads();
    }
    // row-wise sum of squares -> l2norm + mask
    #pragma unroll
    for (int mt=0; mt<2; mt++)
      #pragma unroll
      for (int reg=0; reg<4; reg++) {
        int rl = mt*16 + q*4 + reg;
        float ss = 0.f;
        #pragma unroll
        for (int nt=0; nt<4; nt++){ float v=a2[mt][nt][reg]; ss = fmaf(v,v,ss); }
        ss += __shfl_xor(ss, 1, 64); ss += __shfl_xor(ss, 2, 64);
        ss += __shfl_xor(ss, 4, 64); ss += __shfl_xor(ss, 8, 64);
        if (c==0) rpart[wv][rl] = ss;
      }
    __syncthreads();
    #pragma unroll
    for (int mt=0; mt<2; mt++)
      #pragma unroll
      for (int reg=0; reg<4; reg++) {
        int rl = mt*16 + q*4 + reg;
        float s = rpart[0][rl]+rpart[1][rl]+rpart[2][rl]+rpart[3][rl];
        float inv = (s>0.f)? (1.0f/sqrtf(s)) : 0.f;
        int t = rowT[rl];
        if (t >= rowL[rl]-2) inv = 0.f;
        float* orow = out + FV_OFF + (rowB[rl]*TOUT + t)*256 + colbase;
        #pragma unroll
        for (int nt=0; nt<4; nt++) orow[nt*16] = a2[mt][nt][reg]*inv;
      }
  }
}

extern "C" void kernel_launch(void* const* d_in, const int* in_sizes, int n_in,
                              void* d_out, int out_size, void* d_ws, size_t ws_size,
                              hipStream_t stream) {
  const int*   code    = (const int*)d_in[0];
  const float* others  = (const float*)d_in[1];
  const int*   length  = (const int*)d_in[2];
  const int*   target  = (const int*)d_in[3];
  const int*   widx    = (const int*)d_in[4];
  const float* Wf      = (const float*)d_in[5];
  const float* bfv     = (const float*)d_in[6];
  const float* Wb      = (const float*)d_in[7];
  const float* bbv     = (const float*)d_in[8];
  const float* W0      = (const float*)d_in[9];
  const float* b0v     = (const float*)d_in[10];
  const float* W1      = (const float*)d_in[11];
  const float* b1v     = (const float*)d_in[12];

  u16*   wsu = (u16*)d_ws;
  float* wsf = (float*)d_ws;
  float* out = (float*)d_out;

  prep_kernel<<<dim3(312), dim3(256), 0, stream>>>(target, widx, Wf, bfv, Wb, bbv, W0, W1, wsu, wsf);
  gemm_kernel<<<dim3(396,3), dim3(256), 0, stream>>>(code, others, length,
      b0v, b1v, wsu, wsf, out);
}